// Round 1
// baseline (101577.972 us; speedup 1.0000x reference)
//
#include <hip/hip_runtime.h>
#include <math.h>

#define Bn 128
#define Tn 256
#define Un 1024
#define Ln 256
#define Vn 512
#define G4 4096

// ---------------- embedding gather: x[b,t,:] = emb[tok[b,t],:] ----------------
__global__ void k_embed(const int* __restrict__ tok, const float* __restrict__ emb,
                        float* __restrict__ x) {
  int bt = blockIdx.x;                       // 0..B*T-1
  int t = tok[bt];
  const float4* s = (const float4*)(emb + (long)t * Vn);
  float4* d = (float4*)(x + (long)bt * Vn);
  d[threadIdx.x] = s[threadIdx.x];           // 128 threads * 4 floats = 512
}

// ---- weight reorder: Wcat[k][u*4+g] = (k<Dx ? Wx[k+xrow0][g*1024+u] : Wh[k-Dx][g*1024+u]) ----
__global__ void k_reorder(const float* __restrict__ Wx, const float* __restrict__ Wh,
                          float* __restrict__ out, int Dx, int K, int xrow0) {
  long i = (long)blockIdx.x * blockDim.x + threadIdx.x;
  if (i >= (long)K * G4) return;
  int k = (int)(i >> 12), c = (int)(i & 4095);
  int u = c >> 2, g = c & 3;
  float v;
  if (k < Dx) v = Wx[(long)(k + xrow0) * G4 + g * Un + u];
  else        v = Wh[(long)(k - Dx) * G4 + g * Un + u];
  out[i] = v;
}

// ---------------- fused LSTM layer-step ----------------
// z[128,4096] = [x_t | h_prev] @ Wcat + bias (+ zextra)   then gates -> update c, h
// Block: 32 z-cols (8 u-cols x 4 gates) x 64 rows. Grid: (128 col-blocks, 2 row-blocks).
#define KT 64
#define BR 64
#define PAD 68

__global__ __launch_bounds__(256, 1) void k_lstm_step(
    const float* __restrict__ xin, long xstride, int Dx, int K,
    const float* __restrict__ Wc, const float* __restrict__ hin,
    const float* __restrict__ bias, const float* __restrict__ zextra,
    float* __restrict__ cst, float* __restrict__ hout)
{
  __shared__ float As[2][BR][PAD];
  __shared__ float Ws[2][KT][32];
  int tid = threadIdx.x;
  int cb = blockIdx.x, rb = blockIdx.y;
  int uj = tid & 7, rg = tid >> 3;
  int r0 = rg * 2;
  int la_r = tid >> 2, la_s = tid & 3;       // A loader: row, f4 seg
  long arow = (long)rb * BR + la_r;
  const float* wbase = Wc + cb * 32;
  int e0 = tid * 2, e1 = e0 + 1;             // W loader f4 indices
  float acc[2][4] = {{0.f,0.f,0.f,0.f},{0.f,0.f,0.f,0.f}};
  int nch = K / KT;
  float4 ar0, ar1, ar2, ar3, wr0, wr1;

  // prologue: stage chunk 0
  {
    const float* src; long rs; int ko;
    if (0 < Dx) { src = xin; rs = xstride; ko = 0; } else { src = hin; rs = Un; ko = -Dx; }
    const float* p = src + arow * rs + ko + la_s * 4;
    ar0 = *(const float4*)(p);
    ar1 = *(const float4*)(p + 16);
    ar2 = *(const float4*)(p + 32);
    ar3 = *(const float4*)(p + 48);
    wr0 = *(const float4*)(wbase + (long)(e0 >> 3) * G4 + (e0 & 7) * 4);
    wr1 = *(const float4*)(wbase + (long)(e1 >> 3) * G4 + (e1 & 7) * 4);
    *(float4*)&As[0][la_r][la_s * 4]      = ar0;
    *(float4*)&As[0][la_r][la_s * 4 + 16] = ar1;
    *(float4*)&As[0][la_r][la_s * 4 + 32] = ar2;
    *(float4*)&As[0][la_r][la_s * 4 + 48] = ar3;
    *(float4*)&Ws[0][e0 >> 3][(e0 & 7) * 4] = wr0;
    *(float4*)&Ws[0][e1 >> 3][(e1 & 7) * 4] = wr1;
  }
  __syncthreads();

  for (int ch = 0; ch < nch; ++ch) {
    int buf = ch & 1;
    int nxt = ch + 1;
    if (nxt < nch) {
      int k0 = nxt * KT;
      const float* src; long rs; int ko;
      if (k0 < Dx) { src = xin; rs = xstride; ko = k0; } else { src = hin; rs = Un; ko = k0 - Dx; }
      const float* p = src + arow * rs + ko + la_s * 4;
      ar0 = *(const float4*)(p);
      ar1 = *(const float4*)(p + 16);
      ar2 = *(const float4*)(p + 32);
      ar3 = *(const float4*)(p + 48);
      wr0 = *(const float4*)(wbase + (long)(k0 + (e0 >> 3)) * G4 + (e0 & 7) * 4);
      wr1 = *(const float4*)(wbase + (long)(k0 + (e1 >> 3)) * G4 + (e1 & 7) * 4);
    }
    #pragma unroll
    for (int kk = 0; kk < KT; kk += 4) {
      float4 a0 = *(const float4*)&As[buf][r0][kk];
      float4 a1 = *(const float4*)&As[buf][r0 + 1][kk];
      #pragma unroll
      for (int q = 0; q < 4; ++q) {
        float4 w = *(const float4*)&Ws[buf][kk + q][uj * 4];
        float av0 = (q == 0) ? a0.x : (q == 1) ? a0.y : (q == 2) ? a0.z : a0.w;
        float av1 = (q == 0) ? a1.x : (q == 1) ? a1.y : (q == 2) ? a1.z : a1.w;
        acc[0][0] = fmaf(av0, w.x, acc[0][0]);
        acc[0][1] = fmaf(av0, w.y, acc[0][1]);
        acc[0][2] = fmaf(av0, w.z, acc[0][2]);
        acc[0][3] = fmaf(av0, w.w, acc[0][3]);
        acc[1][0] = fmaf(av1, w.x, acc[1][0]);
        acc[1][1] = fmaf(av1, w.y, acc[1][1]);
        acc[1][2] = fmaf(av1, w.z, acc[1][2]);
        acc[1][3] = fmaf(av1, w.w, acc[1][3]);
      }
    }
    __syncthreads();
    if (nxt < nch) {
      int nb = nxt & 1;
      *(float4*)&As[nb][la_r][la_s * 4]      = ar0;
      *(float4*)&As[nb][la_r][la_s * 4 + 16] = ar1;
      *(float4*)&As[nb][la_r][la_s * 4 + 32] = ar2;
      *(float4*)&As[nb][la_r][la_s * 4 + 48] = ar3;
      *(float4*)&Ws[nb][e0 >> 3][(e0 & 7) * 4] = wr0;
      *(float4*)&Ws[nb][e1 >> 3][(e1 & 7) * 4] = wr1;
    }
    __syncthreads();
  }

  // gates + state update (each (row,u) owned by exactly one thread)
  int u = cb * 8 + uj;
  #pragma unroll
  for (int j = 0; j < 2; ++j) {
    long row = (long)rb * BR + r0 + j;
    float z[4];
    #pragma unroll
    for (int g = 0; g < 4; ++g) {
      float zz = acc[j][g] + bias[g * Un + u];
      if (zextra) zz += zextra[row * G4 + g * Un + u];
      z[g] = zz;
    }
    float ig = 1.f / (1.f + expf(-z[0]));
    float fg = 1.f / (1.f + expf(-z[1]));
    float gg = tanhf(z[2]);
    float og = 1.f / (1.f + expf(-z[3]));
    long idx = row * Un + u;
    float cn = fg * cst[idx] + ig * gg;
    cst[idx] = cn;
    hout[idx] = og * tanhf(cn);
  }
}

// ---------------- mean/sigma -> latent ----------------
__global__ void k_meansig(const float* __restrict__ c3, const float* __restrict__ wm,
                          const float* __restrict__ bm, const float* __restrict__ wsg,
                          const float* __restrict__ bs, const float* __restrict__ eps,
                          float* __restrict__ latent) {
  int b = blockIdx.x;
  int l = threadIdx.x;                       // 256 threads = Ln
  __shared__ float cs[Un];
  for (int uu = threadIdx.x; uu < Un; uu += 256) cs[uu] = c3[(long)b * Un + uu];
  __syncthreads();
  float m = 0.f, s = 0.f;
  for (int uu = 0; uu < Un; ++uu) {
    float cv = cs[uu];
    m = fmaf(cv, wm[(long)uu * Ln + l], m);
    s = fmaf(cv, wsg[(long)uu * Ln + l], s);
  }
  m += bm[l]; s += bs[l];
  latent[(long)b * Ln + l] = m + expf(s * 0.5f) + eps[(long)b * Ln + l];
}

// ---------------- zlat = latent @ dec_Wx0[0:256,:] ----------------
__global__ void k_zlat(const float* __restrict__ latent, const float* __restrict__ Wx0,
                       float* __restrict__ zlat) {
  long idx = (long)blockIdx.x * 256 + threadIdx.x;   // over 128*4096
  int b = (int)(idx >> 12), cc = (int)(idx & 4095);
  const float* lrow = latent + (long)b * Ln;
  float s = 0.f;
  for (int l = 0; l < Ln; ++l) s = fmaf(lrow[l], Wx0[(long)l * G4 + cc], s);
  zlat[idx] = s;
}

// ---------------- logits + argmax for one timestep ----------------
__global__ __launch_bounds__(256) void k_logits(const float* __restrict__ y,
                         const float* __restrict__ w, const float* __restrict__ bias,
                         float* __restrict__ outLogits, float* __restrict__ outArg, int t) {
  int b = blockIdx.x;
  __shared__ float ys[Un];
  __shared__ float rv[256];
  __shared__ int   ri[256];
  for (int uu = threadIdx.x; uu < Un; uu += 256) ys[uu] = y[(long)b * Un + uu];
  __syncthreads();
  float a0 = bias[threadIdx.x], a1 = bias[threadIdx.x + 256];
  for (int uu = 0; uu < Un; ++uu) {
    float yv = ys[uu];
    a0 = fmaf(yv, w[(long)uu * Vn + threadIdx.x], a0);
    a1 = fmaf(yv, w[(long)uu * Vn + threadIdx.x + 256], a1);
  }
  long base = ((long)b * Tn + t) * Vn;
  outLogits[base + threadIdx.x]       = a0;
  outLogits[base + threadIdx.x + 256] = a1;
  float mv; int mi;
  if (a0 >= a1) { mv = a0; mi = threadIdx.x; } else { mv = a1; mi = threadIdx.x + 256; }
  rv[threadIdx.x] = mv; ri[threadIdx.x] = mi;
  __syncthreads();
  for (int s = 128; s > 0; s >>= 1) {
    if (threadIdx.x < s) {
      float ov = rv[threadIdx.x + s]; int oi = ri[threadIdx.x + s];
      if (ov > rv[threadIdx.x] || (ov == rv[threadIdx.x] && oi < ri[threadIdx.x])) {
        rv[threadIdx.x] = ov; ri[threadIdx.x] = oi;
      }
    }
    __syncthreads();
  }
  if (threadIdx.x == 0) outArg[(long)b * Tn + t] = (float)ri[0];
}

// ---------------- host ----------------
extern "C" void kernel_launch(void* const* d_in, const int* in_sizes, int n_in,
                              void* d_out, int out_size, void* d_ws, size_t ws_size,
                              hipStream_t stream) {
  (void)in_sizes; (void)n_in; (void)out_size; (void)ws_size;
  const int*   tokens = (const int*)d_in[0];
  const float* emb    = (const float*)d_in[1];
  const float* eWx[3] = {(const float*)d_in[2], (const float*)d_in[5], (const float*)d_in[8]};
  const float* eWh[3] = {(const float*)d_in[3], (const float*)d_in[6], (const float*)d_in[9]};
  const float* ebv[3] = {(const float*)d_in[4], (const float*)d_in[7], (const float*)d_in[10]};
  const float* dWx[3] = {(const float*)d_in[11], (const float*)d_in[14], (const float*)d_in[17]};
  const float* dWh[3] = {(const float*)d_in[12], (const float*)d_in[15], (const float*)d_in[18]};
  const float* dbv[3] = {(const float*)d_in[13], (const float*)d_in[16], (const float*)d_in[19]};
  const float* w_mean  = (const float*)d_in[20];
  const float* b_mean  = (const float*)d_in[21];
  const float* w_sigma = (const float*)d_in[22];
  const float* b_sigma = (const float*)d_in[23];
  const float* dec_w   = (const float*)d_in[24];
  const float* dec_b   = (const float*)d_in[25];
  const float* eps     = (const float*)d_in[26];
  float* out = (float*)d_out;
  float* outArg    = out;                 // B*T argmax (as float)
  float* outLogits = out + (long)Bn * Tn; // B*T*V logits

  float* ws = (float*)d_ws;
  long off = 0;
  float* x = ws + off; off += (long)Bn * Tn * Vn;       // 16.8M
  int Ks[6] = {1536, 2048, 2048, 1536, 2048, 2048};
  float* Wc[6];
  for (int i = 0; i < 6; ++i) { Wc[i] = ws + off; off += (long)Ks[i] * G4; }
  float* hb = ws + off; off += 12L * Bn * Un;           // h[net][l][parity]
  float* cbuf = ws + off; off += 6L * Bn * Un;          // c[net][l]
  float* latent = ws + off; off += (long)Bn * Ln;
  float* zlat = ws + off; off += (long)Bn * G4;

  #define HBUF(net, l, par) (hb + (((net) * 3 + (l)) * 2 + (par)) * (long)(Bn * Un))
  #define CBUF(net, l)      (cbuf + ((net) * 3 + (l)) * (long)(Bn * Un))

  // prep
  k_embed<<<Bn * Tn, 128, 0, stream>>>(tokens, emb, x);
  {
    int Dxs[6]   = {512, 1024, 1024, 512, 1024, 1024};
    int xr0s[6]  = {0, 0, 0, 256, 0, 0};
    const float* Wxs[6] = {eWx[0], eWx[1], eWx[2], dWx[0], dWx[1], dWx[2]};
    const float* Whs[6] = {eWh[0], eWh[1], eWh[2], dWh[0], dWh[1], dWh[2]};
    for (int i = 0; i < 6; ++i) {
      long n = (long)Ks[i] * G4;
      k_reorder<<<(int)((n + 255) / 256), 256, 0, stream>>>(Wxs[i], Whs[i], Wc[i], Dxs[i], Ks[i], xr0s[i]);
    }
  }
  hipMemsetAsync(hb, 0, 18L * Bn * Un * sizeof(float), stream);  // h + c states

  dim3 gridL(128, 2);
  // encoder
  for (int t = 0; t < Tn; ++t) {
    for (int l = 0; l < 3; ++l) {
      const float* xin; long xs; int Dx;
      if (l == 0) { xin = x + (long)t * Vn; xs = (long)Tn * Vn; Dx = 512; }
      else        { xin = HBUF(0, l - 1, t & 1); xs = Un; Dx = 1024; }
      k_lstm_step<<<gridL, 256, 0, stream>>>(xin, xs, Dx, Dx + 1024, Wc[l],
          HBUF(0, l, (t + 1) & 1), ebv[l], nullptr, CBUF(0, l), HBUF(0, l, t & 1));
    }
  }
  // latent
  k_meansig<<<Bn, 256, 0, stream>>>(CBUF(0, 2), w_mean, b_mean, w_sigma, b_sigma, eps, latent);
  k_zlat<<<(Bn * G4) / 256, 256, 0, stream>>>(latent, dWx[0], zlat);
  // decoder + logits
  for (int t = 0; t < Tn; ++t) {
    for (int l = 0; l < 3; ++l) {
      const float* xin; long xs; int Dx;
      if (l == 0) { xin = x + (long)t * Vn; xs = (long)Tn * Vn; Dx = 512; }
      else        { xin = HBUF(1, l - 1, t & 1); xs = Un; Dx = 1024; }
      k_lstm_step<<<gridL, 256, 0, stream>>>(xin, xs, Dx, Dx + 1024, Wc[3 + l],
          HBUF(1, l, (t + 1) & 1), dbv[l], (l == 0) ? zlat : nullptr, CBUF(1, l), HBUF(1, l, t & 1));
    }
    k_logits<<<Bn, 256, 0, stream>>>(HBUF(1, 2, t & 1), dec_w, dec_b, outLogits, outArg, t);
  }
}